// Round 1
// 111.476 us; speedup vs baseline: 1.3223x; 1.3223x over previous
//
#include <hip/hip_runtime.h>
#include <math.h>

#define Dd 96
#define Nn 48
#define LD 97
#define PTS 98   // even stride: keeps float2 (8 B) LDS loads aligned

// One block per particle k (P f32; R16-verified math).
// R20: latency attack.
//  - rank-4 super-steps now compute the 4x4 panel LU redundantly in REGISTERS
//    (broadcast LDS reads), no wave0 serial prep, ONE barrier per super-step.
//    Row updates use multipliers w = L^-T m against the ORIGINAL panel rows,
//    so rows j+1..j+3 need no trailing update at all (their values are dead).
//  - 512 threads (8 waves): per-wave update rows halve; 2-row manual unroll
//    for memory-level parallelism.
//  - Guards/emission semantics identical to R16/R19.
__global__ __launch_bounds__(512, 2) void slater_kernel(const float* __restrict__ P,
                                                        const int* __restrict__ occ,
                                                        float* __restrict__ out) {
    __shared__ double As[Dd * LD];      // 74,496 B
    __shared__ unsigned char flag[Dd];
    float* PT = (float*)As;             // scratch alias; PT reads end before As writes

    const int tid  = threadIdx.x;
    const int k    = blockIdx.x;
    const int n    = Dd - Nn + k + 1;   // xmax
    const int lane = tid & 63;
    const int wave = tid >> 6;          // 0..7
    const int xmin = (k == 0) ? 0 : occ[k - 1] + 1;

    if (tid < Dd) flag[tid] = 0;
    __syncthreads();
    if (tid < k) flag[occ[tid]] = 1;
    for (int e = tid; e < Dd * Nn; e += 512) {       // PT[t][c] = P[c][t]
        int c = e / Nn, t = e - (e / Nn) * Nn;
        PT[t * PTS + c] = P[e];
    }
    __syncthreads();

    // Build A = I*(1-flag) - P P^T in registers via 2x2 tiles, float2 loads.
    double Areg[20];
#pragma unroll
    for (int it = 0; it < 5; ++it) {
        int tau = tid + 512 * it;
        double s00 = 0.0, s01 = 0.0, s10 = 0.0, s11 = 0.0;
        if (tau < 2304) {
            int tr = tau / 48, tc = tau - (tau / 48) * 48;
            int r0 = 2 * tr, c0 = 2 * tc;
            if (r0 < n && c0 < n) {
                for (int t = 0; t < Nn; ++t) {
                    const float* row = PT + t * PTS;
                    float2 pr = *(const float2*)(row + r0);
                    float2 pc = *(const float2*)(row + c0);
                    s00 -= (double)pr.x * (double)pc.x; s01 -= (double)pr.x * (double)pc.y;
                    s10 -= (double)pr.y * (double)pc.x; s11 -= (double)pr.y * (double)pc.y;
                }
            }
        }
        Areg[it * 4 + 0] = s00; Areg[it * 4 + 1] = s01;
        Areg[it * 4 + 2] = s10; Areg[it * 4 + 3] = s11;
    }
    __syncthreads();                    // all PT reads done before As overwrite
#pragma unroll
    for (int it = 0; it < 5; ++it) {
        int tau = tid + 512 * it;
        if (tau < 2304) {
            int tr = tau / 48, tc = tau - (tau / 48) * 48;
            int r0 = 2 * tr, c0 = 2 * tc;
            if (r0 < n && c0 < n) {
                bool r1ok = (r0 + 1 < n), c1ok = (c0 + 1 < n);
                As[r0 * LD + c0] = Areg[it * 4 + 0] + ((r0 == c0) ? (flag[r0] ? 0.0 : 1.0) : 0.0);
                if (c1ok)
                    As[r0 * LD + c0 + 1] = Areg[it * 4 + 1] + ((r0 == c0 + 1) ? (flag[r0] ? 0.0 : 1.0) : 0.0);
                if (r1ok)
                    As[(r0 + 1) * LD + c0] = Areg[it * 4 + 2] + ((r0 + 1 == c0) ? (flag[r0 + 1] ? 0.0 : 1.0) : 0.0);
                if (r1ok && c1ok)
                    As[(r0 + 1) * LD + c0 + 1] = Areg[it * 4 + 3] + ((r0 + 1 == c0 + 1) ? (flag[r0 + 1] ? 0.0 : 1.0) : 0.0);
            }
        }
    }
    __syncthreads();

    double runprod = 1.0;
    double myprob  = 0.0;
    bool   dead    = false;

    // Guard/emission, identical semantics to R16 (emit BEFORE any cut).
    auto guard = [&](int jj, double pivot) {
        double ap = fabs(pivot);
        if (jj >= xmin) {
            if (tid == jj) myprob = runprod * (1.0 - pivot);
            double newrun = runprod * pivot;
            if (!(ap > 1e-7) || !(ap < 8.0) || !(fabs(newrun) > 1e-8)) dead = true;
            else runprod = newrun;
        } else {
            if (!(ap > 1e-12) || !(ap < 8.0)) dead = true;
        }
    };

    int j = 0;
    // ---- rank-4 super-steps: eliminate cols j..j+3 (all pivots interior) ----
    for (; !dead && j + 4 <= n - 1; j += 4) {
        // 4x4 panel LU, in registers, by EVERY thread (broadcast LDS reads).
        const double* Pr0 = As + j * LD + j;
        const double* Pr1 = As + (j + 1) * LD + j;
        const double* Pr2 = As + (j + 2) * LD + j;
        const double* Pr3 = As + (j + 3) * LD + j;
        double B00 = Pr0[0], B01 = Pr0[1], B02 = Pr0[2], B03 = Pr0[3];
        double B10 = Pr1[0], B11 = Pr1[1], B12 = Pr1[2], B13 = Pr1[3];
        double B20 = Pr2[0], B21 = Pr2[1], B22 = Pr2[2], B23 = Pr2[3];
        double B30 = Pr3[0], B31 = Pr3[1], B32 = Pr3[2], B33 = Pr3[3];

        double piv0 = B00;
        double rp0  = 1.0 / piv0;
        double m10  = B10 * rp0;
        double u01 = B01, u02 = B02, u03 = B03;
        double piv1 = B11 - m10 * u01;
        double u12  = B12 - m10 * u02;
        double u13  = B13 - m10 * u03;
        double rp1  = 1.0 / piv1;
        double m20  = B20 * rp0;
        double m21  = (B21 - m20 * u01) * rp1;
        double piv2 = B22 - m20 * u02 - m21 * u12;
        double u23  = B23 - m20 * u03 - m21 * u13;
        double rp2  = 1.0 / piv2;
        double m30  = B30 * rp0;
        double m31  = (B31 - m30 * u01) * rp1;
        double m32  = (B32 - m30 * u02 - m31 * u12) * rp2;
        double piv3 = B33 - m30 * u03 - m31 * u13 - m32 * u23;
        double rp3  = 1.0 / piv3;

        if (!dead) guard(j + 0, piv0);
        if (!dead) guard(j + 1, piv1);
        if (!dead) guard(j + 2, piv2);
        if (!dead) guard(j + 3, piv3);

        if (!dead) {
            int t = n - (j + 4);
            int c0 = j + 4 + lane, c1 = j + 68 + lane;
            bool ok0 = (lane < t), ok1 = (lane + 64 < t);
            // Original panel rows (NOT modified this super-step).
            double R0c0 = 0.0, R1c0 = 0.0, R2c0 = 0.0, R3c0 = 0.0;
            double R0c1 = 0.0, R1c1 = 0.0, R2c1 = 0.0, R3c1 = 0.0;
            if (ok0) {
                R0c0 = As[j * LD + c0];       R1c0 = As[(j + 1) * LD + c0];
                R2c0 = As[(j + 2) * LD + c0]; R3c0 = As[(j + 3) * LD + c0];
            }
            if (ok1) {
                R0c1 = As[j * LD + c1];       R1c1 = As[(j + 1) * LD + c1];
                R2c1 = As[(j + 2) * LD + c1]; R3c1 = As[(j + 3) * LD + c1];
            }
            // 2-row unrolled update: rows i and i+8 per iteration, loads first.
            for (int i = j + 4 + wave; i < n; i += 16) {
                int ib = i + 8;
                bool hb = (ib < n);
                double* rowA = As + i * LD;
                double a0 = rowA[j], a1 = rowA[j + 1], a2 = rowA[j + 2], a3 = rowA[j + 3];
                double Ta0 = ok0 ? rowA[c0] : 0.0;
                double Ta1 = ok1 ? rowA[c1] : 0.0;
                double* rowB = As + ib * LD;
                double b0 = 0.0, b1 = 0.0, b2 = 0.0, b3 = 0.0, Tb0 = 0.0, Tb1 = 0.0;
                if (hb) {
                    b0 = rowB[j]; b1 = rowB[j + 1]; b2 = rowB[j + 2]; b3 = rowB[j + 3];
                    Tb0 = ok0 ? rowB[c0] : 0.0;
                    Tb1 = ok1 ? rowB[c1] : 0.0;
                }
                // row A: sequential multipliers, then w = L^-T m (back-subst).
                double m0 = a0 * rp0;
                double m1 = (a1 - m0 * u01) * rp1;
                double m2 = (a2 - m0 * u02 - m1 * u12) * rp2;
                double m3 = (a3 - m0 * u03 - m1 * u13 - m2 * u23) * rp3;
                double w3 = m3;
                double w2 = m2 - m32 * w3;
                double w1 = m1 - m21 * w2 - m31 * w3;
                double w0 = m0 - m10 * w1 - m20 * w2 - m30 * w3;
                if (ok0) rowA[c0] = Ta0 - w0 * R0c0 - w1 * R1c0 - w2 * R2c0 - w3 * R3c0;
                if (ok1) rowA[c1] = Ta1 - w0 * R0c1 - w1 * R1c1 - w2 * R2c1 - w3 * R3c1;
                if (hb) {
                    double e0 = b0 * rp0;
                    double e1 = (b1 - e0 * u01) * rp1;
                    double e2 = (b2 - e0 * u02 - e1 * u12) * rp2;
                    double e3 = (b3 - e0 * u03 - e1 * u13 - e2 * u23) * rp3;
                    double v3 = e3;
                    double v2 = e2 - m32 * v3;
                    double v1 = e1 - m21 * v2 - m31 * v3;
                    double v0 = e0 - m10 * v1 - m20 * v2 - m30 * v3;
                    if (ok0) rowB[c0] = Tb0 - v0 * R0c0 - v1 * R1c0 - v2 * R2c0 - v3 * R3c0;
                    if (ok1) rowB[c1] = Tb1 - v0 * R0c1 - v1 * R1c1 - v2 * R2c1 - v3 * R3c1;
                }
            }
        }
        __syncthreads();
    }

    // ---- remainder single steps (R16-proven body, 8-wave stride) ----
    for (; !dead && j < n - 1; ++j) {
        double pivot = As[j * LD + j];
        guard(j, pivot);
        if (dead) break;
        double rp = 1.0 / pivot;
        int t = n - 1 - j;
        double r0 = (lane < t)      ? As[j * LD + j + 1 + lane]  : 0.0;
        double r1 = (lane + 64 < t) ? As[j * LD + j + 65 + lane] : 0.0;
        for (int i = j + 1 + wave; i < n; i += 8) {
            double mult = As[i * LD + j] * rp;
            if (lane < t)      As[i * LD + j + 1 + lane]  -= mult * r0;
            if (lane + 64 < t) As[i * LD + j + 65 + lane] -= mult * r1;
        }
        __syncthreads();
    }
    if (!dead && tid == n - 1) {        // x = xmax-1: remaining mass
        double pl = As[(n - 1) * LD + (n - 1)];
        myprob = runprod * (1.0 - pl);
    }

    if (tid < Dd) {
        double p = myprob;
        if (!isfinite(p)) p = 0.0;
        if (!(fabs(p) > 1e-15)) p = 0.0;   // reference's flush
        p = fmin(fmax(p, 0.0), 1.0);       // junk-proof projection
        out[k * Dd + tid] = (float)p;
    }
}

// prob_sample = prod_k probs[k, occ[k]] — parallel loads + shuffle-tree product.
__global__ void prod_kernel(const int* __restrict__ occ, float* __restrict__ out) {
    int lane = threadIdx.x & 63;
    double v = 1.0;
    if (lane < Nn) v = (double)out[lane * Dd + occ[lane]];
#pragma unroll
    for (int off = 32; off >= 1; off >>= 1)
        v *= __shfl_down(v, off, 64);
    if (lane == 0) {
        if (!isfinite(v)) v = 0.0;
        out[Nn * Dd] = (float)v;
    }
}

extern "C" void kernel_launch(void* const* d_in, const int* in_sizes, int n_in,
                              void* d_out, int out_size, void* d_ws, size_t ws_size,
                              hipStream_t stream) {
    const float* P = (const float*)d_in[0];      // 96x48 f32, row-major
    const int* occ = (const int*)d_in[1];        // 48 int32
    float* out = (float*)d_out;                  // 4609 f32

    slater_kernel<<<Nn, 512, 0, stream>>>(P, occ, out);
    prod_kernel<<<1, 64, 0, stream>>>(occ, out);
}

// Round 2
// 108.251 us; speedup vs baseline: 1.3616x; 1.0298x over previous
//
#include <hip/hip_runtime.h>
#include <math.h>

#define Dd 96
#define Nn 48
#define LD 97
#define PTS 98   // even stride: keeps float2 (8 B) LDS loads aligned

// Fast full-precision f64 reciprocal: v_rcp_f64 + 2 Newton steps.
// Replaces the ~200-cy div_scale/div_fmas/div_fixup sequence (~60 cy).
// <=1 ulp vs IEEE divide; pivots are guard-bounded away from thresholds.
__device__ __forceinline__ double frcp(double x) {
    double r = __builtin_amdgcn_rcp(x);
    r = fma(fma(-x, r, 1.0), r, r);
    r = fma(fma(-x, r, 1.0), r, r);
    return r;
}

// One block per particle k (P f32; R16-verified math).
// R21: latency attack round 2.
//  - frcp for all pivots (4 serial divides/super-step were ~40% of the step).
//  - ALL LDS reads of a super-step (panel B, R-rows) hoisted above the LU
//    chain with clamped addresses; only stores predicated on guards.
//  - 4-row unrolled trailing update (24 loads in flight before any chain).
//  - symmetric build: upper-tri 2x2 tiles only + mirrored writes (build /2).
//  - prod_kernel merged in via d_ws arrival counter (mod-48 trigger is
//    correct for ANY initial counter value -> no memset needed).
__global__ __launch_bounds__(512, 1) void slater_kernel(const float* __restrict__ P,
                                                        const int* __restrict__ occ,
                                                        float* __restrict__ out,
                                                        unsigned* __restrict__ cnt) {
    __shared__ double As[Dd * LD];      // 74,496 B
    __shared__ unsigned char flag[Dd];
    float* PT = (float*)As;             // scratch alias; PT reads end before As writes

    const int tid  = threadIdx.x;
    const int k    = blockIdx.x;
    const int n    = Dd - Nn + k + 1;   // xmax
    const int lane = tid & 63;
    const int wave = tid >> 6;          // 0..7
    const int xmin = (k == 0) ? 0 : occ[k - 1] + 1;

    if (tid < Dd) flag[tid] = 0;
    __syncthreads();
    if (tid < k) flag[occ[tid]] = 1;
    for (int e = tid; e < Dd * Nn; e += 512) {       // PT[t][c] = P[c][t]
        int c = e / Nn, t = e - (e / Nn) * Nn;
        PT[t * PTS + c] = P[e];
    }
    __syncthreads();

    // A = I*(1-flag) - P P^T is SYMMETRIC: compute only upper-tri 2x2 tiles
    // (1176 of 2304), mirror-write the transpose. 512 threads -> 3 partial its.
    double Areg[12]; int trs[3], tcs[3];
#pragma unroll
    for (int it = 0; it < 3; ++it) {
        int tau = tid + 512 * it;
        double s00 = 0.0, s01 = 0.0, s10 = 0.0, s11 = 0.0;
        int tr = 0, tc = 0;
        if (tau < 1176) {
            tr = (int)((97.0 - sqrt(9409.0 - 8.0 * (double)tau)) * 0.5);
            while ((tr * (97 - tr)) / 2 > tau) --tr;            // off(tr) <= tau
            while (((tr + 1) * (96 - tr)) / 2 <= tau) ++tr;     // off(tr+1) > tau
            tc = tr + (tau - (tr * (97 - tr)) / 2);
            int r0 = 2 * tr, c0 = 2 * tc;
            if (r0 < n && c0 < n) {
                for (int t = 0; t < Nn; ++t) {
                    const float* row = PT + t * PTS;
                    float2 pr = *(const float2*)(row + r0);
                    float2 pc = *(const float2*)(row + c0);
                    s00 -= (double)pr.x * (double)pc.x; s01 -= (double)pr.x * (double)pc.y;
                    s10 -= (double)pr.y * (double)pc.x; s11 -= (double)pr.y * (double)pc.y;
                }
            }
        }
        trs[it] = tr; tcs[it] = tc;
        Areg[it * 4 + 0] = s00; Areg[it * 4 + 1] = s01;
        Areg[it * 4 + 2] = s10; Areg[it * 4 + 3] = s11;
    }
    __syncthreads();                    // all PT reads done before As overwrite
#pragma unroll
    for (int it = 0; it < 3; ++it) {
        int tau = tid + 512 * it;
        if (tau < 1176) {
            int tr = trs[it], tc = tcs[it];
            int r0 = 2 * tr, c0 = 2 * tc;
            if (r0 < n && c0 < n) {
                bool r1 = (r0 + 1 < n), c1 = (c0 + 1 < n);
                double d0 = flag[r0] ? 0.0 : 1.0;
                double d1 = flag[r0 + 1] ? 0.0 : 1.0;
                // upper tiles: r0<=c0, both even -> only r0==c0 tiles touch diag
                As[r0 * LD + c0] = Areg[it * 4 + 0] + ((r0 == c0) ? d0 : 0.0);
                if (c1)       As[r0 * LD + c0 + 1]       = Areg[it * 4 + 1];
                if (r1)       As[(r0 + 1) * LD + c0]     = Areg[it * 4 + 2];
                if (r1 && c1) As[(r0 + 1) * LD + c0 + 1] = Areg[it * 4 + 3] + ((r0 == c0) ? d1 : 0.0);
                if (tr != tc) {  // mirror (transpose) write
                    As[c0 * LD + r0] = Areg[it * 4 + 0];
                    if (c1)       As[(c0 + 1) * LD + r0]     = Areg[it * 4 + 1];
                    if (r1)       As[c0 * LD + r0 + 1]       = Areg[it * 4 + 2];
                    if (r1 && c1) As[(c0 + 1) * LD + r0 + 1] = Areg[it * 4 + 3];
                }
            }
        }
    }
    __syncthreads();

    double runprod = 1.0;
    double myprob  = 0.0;
    bool   dead    = false;            // block-uniform

    // Guard/emission, identical semantics to R16 (emit BEFORE any cut).
    auto guard = [&](int jj, double pivot) {
        double ap = fabs(pivot);
        if (jj >= xmin) {
            if (tid == jj) myprob = runprod * (1.0 - pivot);
            double newrun = runprod * pivot;
            if (!(ap > 1e-7) || !(ap < 8.0) || !(fabs(newrun) > 1e-8)) dead = true;
            else runprod = newrun;
        } else {
            if (!(ap > 1e-12) || !(ap < 8.0)) dead = true;
        }
    };

    int j = 0;
    // ---- rank-4 super-steps: eliminate cols j..j+3 (all pivots interior) ----
    for (; !dead && j + 4 <= n - 1; j += 4) {
        // ALL reads first (clamped addrs, unconditional): LDS latency hides
        // under the register LU chain below. dead==false here by loop guard.
        int t = n - (j + 4);
        bool ok0 = (lane < t), ok1 = (lane + 64 < t);
        int c0 = j + 4 + (ok0 ? lane : 0);
        int c1 = j + 4 + (ok1 ? lane + 64 : 0);
        double R0c0 = As[j * LD + c0],       R1c0 = As[(j + 1) * LD + c0];
        double R2c0 = As[(j + 2) * LD + c0], R3c0 = As[(j + 3) * LD + c0];
        double R0c1 = As[j * LD + c1],       R1c1 = As[(j + 1) * LD + c1];
        double R2c1 = As[(j + 2) * LD + c1], R3c1 = As[(j + 3) * LD + c1];

        const double* Bp0 = As + j * LD + j;
        const double* Bp1 = Bp0 + LD;
        const double* Bp2 = Bp1 + LD;
        const double* Bp3 = Bp2 + LD;
        double B00 = Bp0[0], B01 = Bp0[1], B02 = Bp0[2], B03 = Bp0[3];
        double B10 = Bp1[0], B11 = Bp1[1], B12 = Bp1[2], B13 = Bp1[3];
        double B20 = Bp2[0], B21 = Bp2[1], B22 = Bp2[2], B23 = Bp2[3];
        double B30 = Bp3[0], B31 = Bp3[1], B32 = Bp3[2], B33 = Bp3[3];

        // 4x4 panel LU in registers, redundantly in every thread.
        double piv0 = B00;
        double rp0  = frcp(piv0);
        double m10  = B10 * rp0;
        double u01 = B01, u02 = B02, u03 = B03;
        double piv1 = B11 - m10 * u01;
        double u12  = B12 - m10 * u02;
        double u13  = B13 - m10 * u03;
        double rp1  = frcp(piv1);
        double m20  = B20 * rp0;
        double m21  = (B21 - m20 * u01) * rp1;
        double piv2 = B22 - m20 * u02 - m21 * u12;
        double u23  = B23 - m20 * u03 - m21 * u13;
        double rp2  = frcp(piv2);
        double m30  = B30 * rp0;
        double m31  = (B31 - m30 * u01) * rp1;
        double m32  = (B32 - m30 * u02 - m31 * u12) * rp2;
        double piv3 = B33 - m30 * u03 - m31 * u13 - m32 * u23;
        double rp3  = frcp(piv3);

        guard(j + 0, piv0);
        if (!dead) guard(j + 1, piv1);
        if (!dead) guard(j + 2, piv2);
        if (!dead) guard(j + 3, piv3);

        if (!dead) {
            // 4-row unrolled update: all 24 loads in flight before any chain.
            for (int i = j + 4 + wave; i < n; i += 32) {
                double a0[4], a1[4], a2[4], a3[4], T0[4], T1[4];
                bool h[4];
#pragma unroll
                for (int u = 0; u < 4; ++u) {
                    int r = i + u * 8;
                    h[u] = (r < n);
                    const double* rw = As + (h[u] ? r : i) * LD;
                    a0[u] = rw[j];     a1[u] = rw[j + 1];
                    a2[u] = rw[j + 2]; a3[u] = rw[j + 3];
                    T0[u] = rw[c0];    T1[u] = rw[c1];
                }
#pragma unroll
                for (int u = 0; u < 4; ++u) {
                    double m0 = a0[u] * rp0;
                    double m1 = (a1[u] - m0 * u01) * rp1;
                    double m2 = (a2[u] - m0 * u02 - m1 * u12) * rp2;
                    double m3 = (a3[u] - m0 * u03 - m1 * u13 - m2 * u23) * rp3;
                    double w3 = m3;
                    double w2 = m2 - m32 * w3;
                    double w1 = m1 - m21 * w2 - m31 * w3;
                    double w0 = m0 - m10 * w1 - m20 * w2 - m30 * w3;
                    if (h[u]) {
                        double* rw = As + (i + u * 8) * LD;
                        if (ok0) rw[c0] = T0[u] - w0 * R0c0 - w1 * R1c0 - w2 * R2c0 - w3 * R3c0;
                        if (ok1) rw[c1] = T1[u] - w0 * R0c1 - w1 * R1c1 - w2 * R2c1 - w3 * R3c1;
                    }
                }
            }
        }
        __syncthreads();
    }

    // ---- remainder single steps (R16-proven body, 8-wave stride) ----
    for (; !dead && j < n - 1; ++j) {
        double pivot = As[j * LD + j];
        guard(j, pivot);
        if (dead) break;
        double rp = frcp(pivot);
        int t = n - 1 - j;
        double r0 = (lane < t)      ? As[j * LD + j + 1 + lane]  : 0.0;
        double r1 = (lane + 64 < t) ? As[j * LD + j + 65 + lane] : 0.0;
        for (int i = j + 1 + wave; i < n; i += 8) {
            double mult = As[i * LD + j] * rp;
            if (lane < t)      As[i * LD + j + 1 + lane]  -= mult * r0;
            if (lane + 64 < t) As[i * LD + j + 65 + lane] -= mult * r1;
        }
        __syncthreads();
    }
    if (!dead && tid == n - 1) {        // x = xmax-1: remaining mass
        double pl = As[(n - 1) * LD + (n - 1)];
        myprob = runprod * (1.0 - pl);
    }

    if (tid < Dd) {
        double p = myprob;
        if (!isfinite(p)) p = 0.0;
        if (!(fabs(p) > 1e-15)) p = 0.0;   // reference's flush
        p = fmin(fmax(p, 0.0), 1.0);       // junk-proof projection
        out[k * Dd + tid] = (float)p;
    }

    // ---- merged prob_sample: last-arriving block does the product ----
    // Release: my out-row writes -> threadfence -> syncthreads -> lane0 add.
    __threadfence();
    __syncthreads();
    if (wave == 0) {
        int old = 0;
        if (lane == 0)
            old = (int)__hip_atomic_fetch_add(cnt, 1u, __ATOMIC_ACQ_REL,
                                              __HIP_MEMORY_SCOPE_AGENT);
        old = __shfl(old, 0, 64);
        // Exactly one multiple of Nn in any Nn consecutive values -> exactly
        // one trigger per launch for ANY initial/poisoned counter value.
        if (((unsigned)old + 1u) % (unsigned)Nn == 0u) {
            __threadfence();            // acquire side
            double v = 1.0;
            if (lane < Nn) {
                float f = __hip_atomic_load(out + lane * Dd + occ[lane],
                                            __ATOMIC_RELAXED, __HIP_MEMORY_SCOPE_AGENT);
                v = (double)f;
            }
#pragma unroll
            for (int off = 32; off >= 1; off >>= 1)
                v *= __shfl_down(v, off, 64);
            if (lane == 0) {
                if (!isfinite(v)) v = 0.0;
                out[Nn * Dd] = (float)v;
            }
        }
    }
}

extern "C" void kernel_launch(void* const* d_in, const int* in_sizes, int n_in,
                              void* d_out, int out_size, void* d_ws, size_t ws_size,
                              hipStream_t stream) {
    const float* P = (const float*)d_in[0];      // 96x48 f32, row-major
    const int* occ = (const int*)d_in[1];        // 48 int32
    float* out = (float*)d_out;                  // 4609 f32

    slater_kernel<<<Nn, 512, 0, stream>>>(P, occ, out, (unsigned*)d_ws);
}